// Round 8
// baseline (428.499 us; speedup 1.0000x reference)
//
#include <hip/hip_runtime.h>
#include <stdint.h>

// B=131072 rows, K=IN=256, N=OUT=256.
// temp = act @ weight.T (exact int32, |t| < 2^24); r = max|temp|;
// bw = ceil(log2(max(r,1))) (0 if r<=1); shift = bw-7;
// shift>0 ? round_shift(temp,shift) clipped to [-127,127] : int8-wrap(temp)
// exp_out = exp_in + weight_exp + max(shift,0)  (int16 semantics)
// Harness reads d_out as INT32: [B*N values, 1 exp scalar].
//
// R8: k1 latency fixes -- batch all 16 staging loads before packing (1 latency
// exposure, not 8), swap MFMA operands so each lane holds 4 consecutive n
// (dwordx4 epilogue stores, 16 instrs not 64), 1-step B prefetch pipeline.
// k2: exact-cover, 4 batched loads/thread, nt stores.

#define M_ROWS 131072
#define NK 256
#define BM 64
#define AKP 264    // LDS row stride (bf16) = 528 B; 4-bank shift/row -> 2-way (free)

typedef __attribute__((ext_vector_type(8))) short bf16x8;
typedef __attribute__((ext_vector_type(4))) float f32x4;
typedef __attribute__((ext_vector_type(4))) float fv4;
typedef __attribute__((ext_vector_type(4))) int iv4;
typedef __attribute__((ext_vector_type(4))) unsigned int u32x4;
typedef __attribute__((ext_vector_type(4))) unsigned short us4;

__device__ __forceinline__ uint32_t pack_bf16(float a, float b) {
  // exact for integer-valued floats |v| <= 255
  return (__float_as_uint(a) >> 16) | (__float_as_uint(b) & 0xFFFF0000u);
}

// Prepass: weight fp32 -> bf16 (65536 elems; 128 KB, stays L2-resident)
__global__ void wconv(const float* __restrict__ w, unsigned short* __restrict__ wb) {
  const int i = blockIdx.x * 256 + threadIdx.x;
  const fv4 f = ((const fv4*)w)[i];
  us4 o;
  o.x = (unsigned short)(__float_as_uint(f.x) >> 16);
  o.y = (unsigned short)(__float_as_uint(f.y) >> 16);
  o.z = (unsigned short)(__float_as_uint(f.z) >> 16);
  o.w = (unsigned short)(__float_as_uint(f.w) >> 16);
  ((us4*)wb)[i] = o;
}

// k1: full-K single-LDS-stage GEMM; B direct from L2-hot bf16 weight.
// 256 thr = 4 waves; block tile 64 x 256 (full N); wave w: cols w*64..+63.
// MFMA called as mfma(B,A): lane (lm,lk) holds, per (mi,ni), r=0..3:
//   value(m = bm+mi*16+lm, n = wn+ni*16+lk*4+r)  -> iv4 store per (mi,ni).
__global__ __launch_bounds__(256) void gemm_store_max(
    const float* __restrict__ act,           // [M,256] int-valued fp32
    const unsigned short* __restrict__ wgtb, // [256,256] bf16, L2-resident
    int* __restrict__ temp,                  // [M,256] int32 (d_ws)
    int* __restrict__ gmax)                  // [1] global abs-max (pre-zeroed)
{
  __shared__ __align__(16) short As[BM * AKP];   // 33792 B
  __shared__ int smax;

  const int tid = threadIdx.x;
  if (tid == 0) smax = 0;

  const int bm   = blockIdx.x * BM;
  const int lane = tid & 63;
  const int wave = tid >> 6;
  const int lm   = lane & 15;
  const int lk   = lane >> 4;
  const int wn   = wave * 64;

  // ---- stage A: issue ALL 16 global loads, then pack+write ----
  const int arow = tid >> 5;          // 0..7 (+8 per j)
  const int aseg = tid & 31;          // 0..31 (8-float segment)
  const float* pbase = act + (size_t)(bm + arow) * NK + aseg * 8;
  fv4 fr[16];
#pragma unroll
  for (int j = 0; j < 8; ++j) {
    const float* p = pbase + (size_t)(j * 8) * NK;
    fr[2 * j]     = *(const fv4*)p;
    fr[2 * j + 1] = *((const fv4*)p + 1);
  }

  // B fragment base: lane reads wgtb[n = wn+ni*16+lm][kk + lk*8..+8]
  const unsigned short* bbase = wgtb + (size_t)(wn + lm) * NK + lk * 8;
  bf16x8 bcur[4];
#pragma unroll
  for (int ni = 0; ni < 4; ++ni)   // k-step 0 B prefetch (issues early)
    bcur[ni] = *(const bf16x8*)(bbase + (size_t)(ni * 16) * NK);

#pragma unroll
  for (int j = 0; j < 8; ++j) {
    uint32_t pk[4];
    pk[0] = pack_bf16(fr[2 * j].x, fr[2 * j].y);
    pk[1] = pack_bf16(fr[2 * j].z, fr[2 * j].w);
    pk[2] = pack_bf16(fr[2 * j + 1].x, fr[2 * j + 1].y);
    pk[3] = pack_bf16(fr[2 * j + 1].z, fr[2 * j + 1].w);
    *(u32x4*)&As[(arow + j * 8) * AKP + aseg * 8] = *(const u32x4*)pk;
  }
  __syncthreads();   // the only barrier

  f32x4 acc[4][4] = {};

#pragma unroll
  for (int k8 = 0; k8 < 8; ++k8) {
    bf16x8 bnxt[4];
    if (k8 < 7) {
      const int kkn = (k8 + 1) * 32;
#pragma unroll
      for (int ni = 0; ni < 4; ++ni)
        bnxt[ni] = *(const bf16x8*)(bbase + (size_t)(ni * 16) * NK + kkn);
    }
    const int kk = k8 * 32;
    bf16x8 af[4];
#pragma unroll
    for (int mi = 0; mi < 4; ++mi)
      af[mi] = *(const bf16x8*)&As[(mi * 16 + lm) * AKP + kk + lk * 8];
#pragma unroll
    for (int mi = 0; mi < 4; ++mi)
#pragma unroll
      for (int ni = 0; ni < 4; ++ni)
        acc[mi][ni] = __builtin_amdgcn_mfma_f32_16x16x32_bf16(
            bcur[ni], af[mi], acc[mi][ni], 0, 0, 0);   // transposed C
    if (k8 < 7) {
#pragma unroll
      for (int ni = 0; ni < 4; ++ni) bcur[ni] = bnxt[ni];
    }
  }

  // Epilogue: lane holds 4 consecutive n per (mi,ni) -> dwordx4 stores.
  int imax = 0;
#pragma unroll
  for (int mi = 0; mi < 4; ++mi) {
    const size_t rowoff = (size_t)(bm + mi * 16 + lm) * NK;
#pragma unroll
    for (int ni = 0; ni < 4; ++ni) {
      iv4 qv;
#pragma unroll
      for (int r = 0; r < 4; ++r) {
        const int iv = (int)acc[mi][ni][r];
        qv[r] = iv;
        const int a = iv < 0 ? -iv : iv;
        imax = a > imax ? a : imax;
      }
      *(iv4*)&temp[rowoff + wn + ni * 16 + lk * 4] = qv;
    }
  }
#pragma unroll
  for (int off = 32; off; off >>= 1) {
    const int o = __shfl_xor(imax, off, 64);
    imax = o > imax ? o : imax;
  }
  if (lane == 0) atomicMax(&smax, imax);
  __syncthreads();
  if (tid == 0) atomicMax(gmax, smax);
}

// k2: streaming quantize temp (LLC-hot) -> out (nt). Exact cover:
// 8192 blocks x 256 thr x 4 iv4 (64 B) per thread, loads batched.
__global__ __launch_bounds__(256) void quant_stream(
    const int* __restrict__ temp, int* __restrict__ out,
    const int* __restrict__ gmax,
    const int* __restrict__ exp_in, const int* __restrict__ wexp)
{
  const int r = *gmax;
  const int bw = (r <= 1) ? 0 : (32 - __clz(r - 1));   // ceil(log2(r))
  const int shift = bw - 7;
  const bool pos = shift > 0;
  const int s = shift < 1 ? 1 : shift;

  const size_t t = (size_t)blockIdx.x * 256 + threadIdx.x;
  const iv4* pin = (const iv4*)temp + t * 4;
  iv4* pout = (iv4*)out + t * 4;

  iv4 v[4];
#pragma unroll
  for (int j = 0; j < 4; ++j) v[j] = pin[j];   // 4 independent loads in flight

#pragma unroll
  for (int j = 0; j < 4; ++j) {
    iv4 o;
#pragma unroll
    for (int e = 0; e < 4; ++e) {
      const int ti = v[j][e];
      int q;
      if (pos) {
        const int rt = ti >> s;                       // floor(t / 2^s)
        const int dec = (ti - (rt << s)) >> (s - 1);  // {0,1}
        q = rt + dec;
        q = q > 127 ? 127 : (q < -127 ? -127 : q);
      } else {
        q = (int)(signed char)(ti & 0xFF);            // int8 wrap
      }
      o[e] = q;
    }
    __builtin_nontemporal_store(o, &pout[j]);
  }

  if (t == 0) {
    const int e = exp_in[0] + wexp[0] + (pos ? shift : 0);
    out[(size_t)M_ROWS * NK] = (int)(short)e;
  }
}

extern "C" void kernel_launch(void* const* d_in, const int* in_sizes, int n_in,
                              void* d_out, int out_size, void* d_ws, size_t ws_size,
                              hipStream_t stream) {
  const float* act   = (const float*)d_in[0];
  const int* exp_in  = (const int*)d_in[1];
  const float* wgt   = (const float*)d_in[2];
  const int* wexp    = (const int*)d_in[3];

  int* gmax          = (int*)d_ws;
  unsigned short* wb = (unsigned short*)((char*)d_ws + 4096);        // 128 KB
  int* temp          = (int*)((char*)d_ws + (1 << 20));              // 134 MB

  (void)hipMemsetAsync(d_ws, 0, sizeof(int), stream);
  wconv<<<dim3(64), dim3(256), 0, stream>>>(wgt, wb);
  gemm_store_max<<<dim3(M_ROWS / BM), dim3(256), 0, stream>>>(act, wb, temp, gmax);
  quant_stream<<<dim3(8192), dim3(256), 0, stream>>>(temp, (int*)d_out, gmax,
                                                     exp_in, wexp);
}

// Round 9
// 290.438 us; speedup vs baseline: 1.4754x; 1.4754x over previous
//
#include <hip/hip_runtime.h>
#include <stdint.h>

// B=131072 rows, K=IN=256, N=OUT=256.
// temp = act @ weight.T (exact int32, |t| < 2^24); r = max|temp|;
// bw = ceil(log2(max(r,1))) (0 if r<=1); shift = bw-7;
// shift>0 ? round_shift(temp,shift) clipped to [-127,127] : int8-wrap(temp)
// exp_out = exp_in + weight_exp + max(shift,0)  (int16 semantics)
// Harness reads d_out as INT32: [B*N values, 1 exp scalar].
//
// R9: fix R8's quant_stream coalescing regression (blocked 64B/thread ->
// WRITE_SIZE 359MB for a 134MB output). Interleaved: thread t, iter j ->
// iv4 index block*1024 + j*256 + tid; each wave store = 1024B contiguous.
// gemm_store_max unchanged from R8.

#define M_ROWS 131072
#define NK 256
#define BM 64
#define AKP 264    // LDS row stride (bf16) = 528 B; 4-bank shift/row -> 2-way (free)

typedef __attribute__((ext_vector_type(8))) short bf16x8;
typedef __attribute__((ext_vector_type(4))) float f32x4;
typedef __attribute__((ext_vector_type(4))) float fv4;
typedef __attribute__((ext_vector_type(4))) int iv4;
typedef __attribute__((ext_vector_type(4))) unsigned int u32x4;
typedef __attribute__((ext_vector_type(4))) unsigned short us4;

__device__ __forceinline__ uint32_t pack_bf16(float a, float b) {
  // exact for integer-valued floats |v| <= 255
  return (__float_as_uint(a) >> 16) | (__float_as_uint(b) & 0xFFFF0000u);
}

// Prepass: weight fp32 -> bf16 (65536 elems; 128 KB, stays L2-resident)
__global__ void wconv(const float* __restrict__ w, unsigned short* __restrict__ wb) {
  const int i = blockIdx.x * 256 + threadIdx.x;
  const fv4 f = ((const fv4*)w)[i];
  us4 o;
  o.x = (unsigned short)(__float_as_uint(f.x) >> 16);
  o.y = (unsigned short)(__float_as_uint(f.y) >> 16);
  o.z = (unsigned short)(__float_as_uint(f.z) >> 16);
  o.w = (unsigned short)(__float_as_uint(f.w) >> 16);
  ((us4*)wb)[i] = o;
}

// k1: full-K single-LDS-stage GEMM; B direct from L2-hot bf16 weight.
// 256 thr = 4 waves; block tile 64 x 256 (full N); wave w: cols w*64..+63.
// MFMA called as mfma(B,A): lane (lm,lk) holds, per (mi,ni), r=0..3:
//   value(m = bm+mi*16+lm, n = wn+ni*16+lk*4+r)  -> iv4 store per (mi,ni).
__global__ __launch_bounds__(256) void gemm_store_max(
    const float* __restrict__ act,           // [M,256] int-valued fp32
    const unsigned short* __restrict__ wgtb, // [256,256] bf16, L2-resident
    int* __restrict__ temp,                  // [M,256] int32 (d_ws)
    int* __restrict__ gmax)                  // [1] global abs-max (pre-zeroed)
{
  __shared__ __align__(16) short As[BM * AKP];   // 33792 B
  __shared__ int smax;

  const int tid = threadIdx.x;
  if (tid == 0) smax = 0;

  const int bm   = blockIdx.x * BM;
  const int lane = tid & 63;
  const int wave = tid >> 6;
  const int lm   = lane & 15;
  const int lk   = lane >> 4;
  const int wn   = wave * 64;

  // ---- stage A: issue ALL 16 global loads, then pack+write ----
  const int arow = tid >> 5;          // 0..7 (+8 per j)
  const int aseg = tid & 31;          // 0..31 (8-float segment)
  const float* pbase = act + (size_t)(bm + arow) * NK + aseg * 8;
  fv4 fr[16];
#pragma unroll
  for (int j = 0; j < 8; ++j) {
    const float* p = pbase + (size_t)(j * 8) * NK;
    fr[2 * j]     = *(const fv4*)p;
    fr[2 * j + 1] = *((const fv4*)p + 1);
  }

  // B fragment base: lane reads wgtb[n = wn+ni*16+lm][kk + lk*8..+8]
  const unsigned short* bbase = wgtb + (size_t)(wn + lm) * NK + lk * 8;
  bf16x8 bcur[4];
#pragma unroll
  for (int ni = 0; ni < 4; ++ni)   // k-step 0 B prefetch (issues early)
    bcur[ni] = *(const bf16x8*)(bbase + (size_t)(ni * 16) * NK);

#pragma unroll
  for (int j = 0; j < 8; ++j) {
    uint32_t pk[4];
    pk[0] = pack_bf16(fr[2 * j].x, fr[2 * j].y);
    pk[1] = pack_bf16(fr[2 * j].z, fr[2 * j].w);
    pk[2] = pack_bf16(fr[2 * j + 1].x, fr[2 * j + 1].y);
    pk[3] = pack_bf16(fr[2 * j + 1].z, fr[2 * j + 1].w);
    *(u32x4*)&As[(arow + j * 8) * AKP + aseg * 8] = *(const u32x4*)pk;
  }
  __syncthreads();   // the only barrier

  f32x4 acc[4][4] = {};

#pragma unroll
  for (int k8 = 0; k8 < 8; ++k8) {
    bf16x8 bnxt[4];
    if (k8 < 7) {
      const int kkn = (k8 + 1) * 32;
#pragma unroll
      for (int ni = 0; ni < 4; ++ni)
        bnxt[ni] = *(const bf16x8*)(bbase + (size_t)(ni * 16) * NK + kkn);
    }
    const int kk = k8 * 32;
    bf16x8 af[4];
#pragma unroll
    for (int mi = 0; mi < 4; ++mi)
      af[mi] = *(const bf16x8*)&As[(mi * 16 + lm) * AKP + kk + lk * 8];
#pragma unroll
    for (int mi = 0; mi < 4; ++mi)
#pragma unroll
      for (int ni = 0; ni < 4; ++ni)
        acc[mi][ni] = __builtin_amdgcn_mfma_f32_16x16x32_bf16(
            bcur[ni], af[mi], acc[mi][ni], 0, 0, 0);   // transposed C
    if (k8 < 7) {
#pragma unroll
      for (int ni = 0; ni < 4; ++ni) bcur[ni] = bnxt[ni];
    }
  }

  // Epilogue: lane holds 4 consecutive n per (mi,ni) -> dwordx4 stores.
  int imax = 0;
#pragma unroll
  for (int mi = 0; mi < 4; ++mi) {
    const size_t rowoff = (size_t)(bm + mi * 16 + lm) * NK;
#pragma unroll
    for (int ni = 0; ni < 4; ++ni) {
      iv4 qv;
#pragma unroll
      for (int r = 0; r < 4; ++r) {
        const int iv = (int)acc[mi][ni][r];
        qv[r] = iv;
        const int a = iv < 0 ? -iv : iv;
        imax = a > imax ? a : imax;
      }
      *(iv4*)&temp[rowoff + wn + ni * 16 + lk * 4] = qv;
    }
  }
#pragma unroll
  for (int off = 32; off; off >>= 1) {
    const int o = __shfl_xor(imax, off, 64);
    imax = o > imax ? o : imax;
  }
  if (lane == 0) atomicMax(&smax, imax);
  __syncthreads();
  if (tid == 0) atomicMax(gmax, smax);
}

// k2: streaming quantize temp (LLC-hot) -> out (nt). 8192 blocks x 256 thr,
// 4 iv4/thread INTERLEAVED: idx = block*1024 + j*256 + tid (coalesced:
// each wave instruction covers 1024 contiguous bytes).
__global__ __launch_bounds__(256) void quant_stream(
    const int* __restrict__ temp, int* __restrict__ out,
    const int* __restrict__ gmax,
    const int* __restrict__ exp_in, const int* __restrict__ wexp)
{
  const int r = *gmax;
  const int bw = (r <= 1) ? 0 : (32 - __clz(r - 1));   // ceil(log2(r))
  const int shift = bw - 7;
  const bool pos = shift > 0;
  const int s = shift < 1 ? 1 : shift;

  const int base = blockIdx.x * 1024 + threadIdx.x;
  const iv4* pin = (const iv4*)temp;
  iv4* pout = (iv4*)out;

  iv4 v[4];
#pragma unroll
  for (int j = 0; j < 4; ++j) v[j] = pin[base + j * 256];   // 4 loads in flight

#pragma unroll
  for (int j = 0; j < 4; ++j) {
    iv4 o;
#pragma unroll
    for (int e = 0; e < 4; ++e) {
      const int ti = v[j][e];
      int q;
      if (pos) {
        const int rt = ti >> s;                       // floor(t / 2^s)
        const int dec = (ti - (rt << s)) >> (s - 1);  // {0,1}
        q = rt + dec;
        q = q > 127 ? 127 : (q < -127 ? -127 : q);
      } else {
        q = (int)(signed char)(ti & 0xFF);            // int8 wrap
      }
      o[e] = q;
    }
    __builtin_nontemporal_store(o, &pout[base + j * 256]);
  }

  if (base == 0) {
    const int e = exp_in[0] + wexp[0] + (pos ? shift : 0);
    out[(size_t)M_ROWS * NK] = (int)(short)e;
  }
}

extern "C" void kernel_launch(void* const* d_in, const int* in_sizes, int n_in,
                              void* d_out, int out_size, void* d_ws, size_t ws_size,
                              hipStream_t stream) {
  const float* act   = (const float*)d_in[0];
  const int* exp_in  = (const int*)d_in[1];
  const float* wgt   = (const float*)d_in[2];
  const int* wexp    = (const int*)d_in[3];

  int* gmax          = (int*)d_ws;
  unsigned short* wb = (unsigned short*)((char*)d_ws + 4096);        // 128 KB
  int* temp          = (int*)((char*)d_ws + (1 << 20));              // 134 MB

  (void)hipMemsetAsync(d_ws, 0, sizeof(int), stream);
  wconv<<<dim3(64), dim3(256), 0, stream>>>(wgt, wb);
  gemm_store_max<<<dim3(M_ROWS / BM), dim3(256), 0, stream>>>(act, wb, temp, gmax);
  quant_stream<<<dim3(8192), dim3(256), 0, stream>>>(temp, (int*)d_out, gmax,
                                                     exp_in, wexp);
}